// Round 7
// baseline (519.014 us; speedup 1.0000x reference)
//
#include <hip/hip_runtime.h>
#include <stdint.h>

#define S_LEN 2048
#define D_MODELX 768
#define N_HEADS 12
#define HEAD_D 64
#define BATCHX 4
#define M_ROWS (BATCHX * S_LEN)  // 8192

typedef __attribute__((ext_vector_type(8))) short bf16x8;
typedef __attribute__((ext_vector_type(4))) short s16x4;
typedef __attribute__((ext_vector_type(4))) float f32x4;
typedef __attribute__((ext_vector_type(16))) float f32x16;
typedef __attribute__((ext_vector_type(4))) uint32_t u32x4;

__device__ __forceinline__ short bf16_rne(float f) {
  uint32_t u = __builtin_bit_cast(uint32_t, f);
  u += 0x7FFFu + ((u >> 16) & 1u);
  return (short)(u >> 16);
}

__device__ __forceinline__ void gload_lds16(const void* g, void* l) {
  __builtin_amdgcn_global_load_lds((const __attribute__((address_space(1))) void*)g,
                                   (__attribute__((address_space(3))) void*)l, 16, 0, 0);
}

// ---------------- fused fp32 -> bf16 convert (X + 4 weight matrices) ----------------
__global__ __launch_bounds__(256) void convert_all(
    const float4* __restrict__ X,
    const float4* __restrict__ Wq, const float4* __restrict__ Wk,
    const float4* __restrict__ Wv, const float4* __restrict__ Wy,
    s16x4* __restrict__ Xb,
    s16x4* __restrict__ Wqb, s16x4* __restrict__ Wkb,
    s16x4* __restrict__ Wvb, s16x4* __restrict__ Wyb)
{
  const int NX = M_ROWS * D_MODELX / 4;
  const int NW = D_MODELX * D_MODELX / 4;
  const int NT = NX + 4 * NW;
  const int stride = gridDim.x * blockDim.x;
  for (int i = blockIdx.x * blockDim.x + threadIdx.x; i < NT; i += stride) {
    const float4* src; s16x4* dst; int off;
    if (i < NX)               { src = X;  dst = Xb;  off = i; }
    else if (i < NX + NW)     { src = Wq; dst = Wqb; off = i - NX; }
    else if (i < NX + 2*NW)   { src = Wk; dst = Wkb; off = i - NX - NW; }
    else if (i < NX + 3*NW)   { src = Wv; dst = Wvb; off = i - NX - 2*NW; }
    else                      { src = Wy; dst = Wyb; off = i - NX - 3*NW; }
    float4 v = src[off];
    s16x4 o;
    o.x = bf16_rne(v.x); o.y = bf16_rne(v.y); o.z = bf16_rne(v.z); o.w = bf16_rne(v.w);
    dst[off] = o;
  }
}

// ---------------- bf16 GEMM:  Out[M,N] = A[M,K] @ W[N,K]^T + bias ----------------
// 128x128 tile, BK=32, 4 waves (2x2), 16x16x32 MFMA, global_load_lds staging, dbuf.
// VTOUT: for z==2 (V projection) write output directly transposed as VT[b][h][d][s].
template<bool OUTF32, bool VTOUT>
__global__ __launch_bounds__(256) void gemm_kernel(
    const short* __restrict__ A,
    const short* __restrict__ W0, const short* __restrict__ W1, const short* __restrict__ W2,
    const float* __restrict__ b0, const float* __restrict__ b1, const float* __restrict__ b2,
    void* __restrict__ O0, void* __restrict__ O1, void* __restrict__ O2,
    float scale0)
{
  const int K = D_MODELX, N = D_MODELX;
  const int z = blockIdx.z;
  const short* W    = (z == 0) ? W0 : ((z == 1) ? W1 : W2);
  const float* bias = (z == 0) ? b0 : ((z == 1) ? b1 : b2);
  void* Op          = (z == 0) ? O0 : ((z == 1) ? O1 : O2);
  const float scale = (z == 0) ? scale0 : 1.0f;

  const int tid = threadIdx.x;
  const int lane = tid & 63;
  const int wv = tid >> 6;
  const int wm = wv >> 1, wn = wv & 1;
  const int r = lane & 15, g = lane >> 4;

  const int m0 = blockIdx.x * 128;
  const int n0 = blockIdx.y * 128;

  __shared__ short As[2][128 * 32];
  __shared__ short Bs[2][128 * 32];

  const f32x4 fzero = {0.f, 0.f, 0.f, 0.f};
  f32x4 acc[4][4];
  #pragma unroll
  for (int i = 0; i < 4; ++i)
    #pragma unroll
    for (int j = 0; j < 4; ++j) acc[i][j] = fzero;

  const int row_s = lane >> 2;
  const int colb  = (lane & 3) * 16;

  auto stage = [&](int buf, int kt) {
    const int kc = kt * 32;
    #pragma unroll
    for (int it = 0; it < 2; ++it) {
      int chunk = wv * 2 + it;
      int row = chunk * 16 + row_s;
      const char* gA = (const char*)(A + (size_t)(m0 + row) * K + kc) + colb;
      const char* gB = (const char*)(W + (size_t)(n0 + row) * K + kc) + colb;
      gload_lds16(gA, (char*)(&As[buf][0]) + chunk * 1024);
      gload_lds16(gB, (char*)(&Bs[buf][0]) + chunk * 1024);
    }
  };

  const int NTK = K / 32;
  stage(0, 0);
  asm volatile("s_waitcnt vmcnt(0)");
  __syncthreads();

  int cur = 0;
  for (int kt = 0; kt < NTK; ++kt) {
    if (kt + 1 < NTK) stage(cur ^ 1, kt + 1);
    bf16x8 af[4], bfr[4];
    #pragma unroll
    for (int i = 0; i < 4; ++i)
      af[i] = *(const bf16x8*)(&As[cur][(wm * 64 + i * 16 + r) * 32 + g * 8]);
    #pragma unroll
    for (int j = 0; j < 4; ++j)
      bfr[j] = *(const bf16x8*)(&Bs[cur][(wn * 64 + j * 16 + r) * 32 + g * 8]);
    #pragma unroll
    for (int i = 0; i < 4; ++i)
      #pragma unroll
      for (int j = 0; j < 4; ++j)
        acc[i][j] = __builtin_amdgcn_mfma_f32_16x16x32_bf16(af[i], bfr[j], acc[i][j], 0, 0, 0);
    asm volatile("s_waitcnt vmcnt(0)");
    __syncthreads();
    cur ^= 1;
  }

  if (VTOUT && z == 2) {
    // V projection: store transposed VT[((b*NH+h)*64+d)*S + s], 4 consecutive s packed.
    #pragma unroll
    for (int j = 0; j < 4; ++j) {
      const int col = n0 + wn * 64 + j * 16 + r;
      const float bv_ = bias[col];
      const int hh = col >> 6, dd = col & 63;
      #pragma unroll
      for (int i = 0; i < 4; ++i) {
        const int rowb = m0 + wm * 64 + i * 16 + g * 4;
        const int bb = rowb >> 11, ss = rowb & 2047;
        s16x4 pk;
        #pragma unroll
        for (int e = 0; e < 4; ++e) pk[e] = bf16_rne(acc[i][j][e] + bv_);
        *(s16x4*)((short*)Op + ((size_t)(bb * N_HEADS + hh) * HEAD_D + dd) * S_LEN + ss) = pk;
      }
    }
    return;
  }

  #pragma unroll
  for (int j = 0; j < 4; ++j) {
    const int col = n0 + wn * 64 + j * 16 + r;
    const float bv_ = bias[col];
    #pragma unroll
    for (int i = 0; i < 4; ++i) {
      const int rowb = m0 + wm * 64 + i * 16 + g * 4;
      #pragma unroll
      for (int e = 0; e < 4; ++e) {
        float v = (acc[i][j][e] + bv_) * scale;
        if (OUTF32) ((float*)Op)[(size_t)(rowb + e) * N + col] = v;
        else        ((short*)Op)[(size_t)(rowb + e) * N + col] = bf16_rne(v);
      }
    }
  }
}

// ---------------- flash attention v2: swapped QK^T, 32 q-rows/wave, KVBLK=64 -------
// Q pre-scaled by 0.125*log2(e). S^T = mfma(A=K, B=Q): lane holds P row q=lane&31,
// kv = 32t + (r&3) + 8*(r>>2) + 4*hi (r=reg 0..15, hi=lane>>5).
// PV uses permuted-kv MFMA steps so A-frags are pure in-lane repacks of own P.
__global__ __launch_bounds__(256) void attn2(
    const short* __restrict__ Q, const short* __restrict__ K,
    const short* __restrict__ VT, const int* __restrict__ mask,
    short* __restrict__ O)
{
  const int b = blockIdx.z, h = blockIdx.y;
  const int lane = threadIdx.x & 63, wv = threadIdx.x >> 6;
  const int qc = lane & 31;           // q (QK^T B-col) / kv row (A) / d col (PV B)
  const int hi = lane >> 5;
  const int q0 = blockIdx.x * 128 + wv * 32;
  const size_t hb  = (size_t)b * S_LEN * D_MODELX + h * HEAD_D;
  const size_t vtb = (size_t)(b * N_HEADS + h) * HEAD_D * S_LEN;

  __shared__ float Abuf[4][32];
  __shared__ float Lbuf[4][32];

  // Q B-frags (hoisted): Q[q0+qc][d = c*16 + hi*8 + j]
  bf16x8 qf[4];
  #pragma unroll
  for (int c = 0; c < 4; ++c)
    qf[c] = *(const bf16x8*)(Q + hb + (size_t)(q0 + qc) * D_MODELX + c * 16 + hi * 8);

  const short* vrow0 = VT + vtb + (size_t)qc * S_LEN;         // d = qc
  const short* vrow1 = VT + vtb + (size_t)(32 + qc) * S_LEN;  // d = qc+32

  f32x16 o0 = {}, o1 = {};
  float mr = -1e30f, lr = 0.f;
  const int* mrow = mask + (size_t)b * S_LEN;

  for (int kv0 = 0; kv0 < S_LEN; kv0 += 64) {
    // ---- QK^T (swapped): 2 S^T tiles of 32kv x 32q ----
    f32x16 s[2];
    #pragma unroll
    for (int t = 0; t < 2; ++t) {
      const short* krow = K + hb + (size_t)(kv0 + 32 * t + qc) * D_MODELX + hi * 8;
      f32x16 acc = {};
      #pragma unroll
      for (int c = 0; c < 4; ++c) {
        bf16x8 kf = *(const bf16x8*)(krow + c * 16);
        acc = __builtin_amdgcn_mfma_f32_32x32x16_bf16(kf, qf[c], acc, 0, 0, 0);
      }
      s[t] = acc;
    }

    // ---- mask (fast path: no zeros in this 64-kv tile) ----
    unsigned long long bal = __ballot(mrow[kv0 + lane] == 0);
    if (bal) {
      #pragma unroll
      for (int t = 0; t < 2; ++t)
        #pragma unroll
        for (int r = 0; r < 16; ++r) {
          int kvoff = 32 * t + (r & 3) + 8 * (r >> 2) + 4 * hi;
          if ((bal >> kvoff) & 1ull) s[t][r] = -1e30f;
        }
    }

    // ---- online softmax (scores already in log2 units) ----
    float bm = -1e30f;
    #pragma unroll
    for (int t = 0; t < 2; ++t)
      #pragma unroll
      for (int r = 0; r < 16; ++r) bm = fmaxf(bm, s[t][r]);
    bm = fmaxf(bm, __shfl_xor(bm, 32));

    if (!__all(bm <= mr + 8.0f)) {   // rescale path (rare after warmup)
      float mnew = fmaxf(mr, bm);
      float alpha = __builtin_amdgcn_exp2f(mr - mnew);
      mr = mnew;
      lr *= alpha;
      if (hi == 0) Abuf[wv][qc] = alpha;
      float av[16];
      #pragma unroll
      for (int r = 0; r < 16; ++r)
        av[r] = Abuf[wv][(r & 3) + 8 * (r >> 2) + 4 * hi];
      #pragma unroll
      for (int r = 0; r < 16; ++r) { o0[r] *= av[r]; o1[r] *= av[r]; }
    }

    float rs = 0.f;
    #pragma unroll
    for (int t = 0; t < 2; ++t)
      #pragma unroll
      for (int r = 0; r < 16; ++r) {
        float p = __builtin_amdgcn_exp2f(s[t][r] - mr);
        s[t][r] = p;
        rs += p;
      }
    lr += rs;

    // ---- pack P -> bf16 words (in-lane; w[t][m] = pk(p[2m], p[2m+1])) ----
    uint32_t w[2][8];
    #pragma unroll
    for (int t = 0; t < 2; ++t)
      #pragma unroll
      for (int m = 0; m < 8; ++m)
        asm("v_cvt_pk_bf16_f32 %0, %1, %2"
            : "=v"(w[t][m]) : "v"(s[t][2 * m]), "v"(s[t][2 * m + 1]));

    // ---- PV: permuted-kv steps; A = own packed P, B = V^T 2x8B loads ----
    #pragma unroll
    for (int t = 0; t < 2; ++t)
      #pragma unroll
      for (int u = 0; u < 2; ++u) {
        u32x4 fw = {w[t][4 * u], w[t][4 * u + 1], w[t][4 * u + 2], w[t][4 * u + 3]};
        bf16x8 pa = __builtin_bit_cast(bf16x8, fw);
        const int kvb = kv0 + 32 * t + 16 * u + 4 * hi;
        s16x4 a0 = *(const s16x4*)(vrow0 + kvb);
        s16x4 a1 = *(const s16x4*)(vrow0 + kvb + 8);
        bf16x8 vf0 = __builtin_shufflevector(a0, a1, 0, 1, 2, 3, 4, 5, 6, 7);
        o0 = __builtin_amdgcn_mfma_f32_32x32x16_bf16(pa, vf0, o0, 0, 0, 0);
        s16x4 b0 = *(const s16x4*)(vrow1 + kvb);
        s16x4 b1 = *(const s16x4*)(vrow1 + kvb + 8);
        bf16x8 vf1 = __builtin_shufflevector(b0, b1, 0, 1, 2, 3, 4, 5, 6, 7);
        o1 = __builtin_amdgcn_mfma_f32_32x32x16_bf16(pa, vf1, o1, 0, 0, 0);
      }
  }

  // ---- epilogue: combine l halves, normalize, store ----
  float ltot = lr + __shfl_xor(lr, 32);
  if (hi == 0) Lbuf[wv][qc] = ltot;
  #pragma unroll
  for (int r = 0; r < 16; ++r) {
    float inv = 1.0f / Lbuf[wv][(r & 3) + 8 * (r >> 2) + 4 * hi];
    int q = q0 + (r & 3) + 8 * (r >> 2) + 4 * hi;
    O[hb + (size_t)q * D_MODELX + qc]      = bf16_rne(o0[r] * inv);
    O[hb + (size_t)q * D_MODELX + 32 + qc] = bf16_rne(o1[r] * inv);
  }
}

// ---------------- host launch ----------------
extern "C" void kernel_launch(void* const* d_in, const int* in_sizes, int n_in,
                              void* d_out, int out_size, void* d_ws, size_t ws_size,
                              hipStream_t stream)
{
  const float* hs = (const float*)d_in[0];
  const int* mask = (const int*)d_in[1];
  const float* Wq = (const float*)d_in[2];
  const float* bq = (const float*)d_in[3];
  const float* Wk = (const float*)d_in[4];
  const float* bk = (const float*)d_in[5];
  const float* Wv = (const float*)d_in[6];
  const float* bv = (const float*)d_in[7];
  const float* Wy = (const float*)d_in[8];
  const float* by = (const float*)d_in[9];

  char* ws = (char*)d_ws;
  const size_t SZ_X = (size_t)M_ROWS * D_MODELX * 2;    // 12.6 MB
  const size_t SZ_W = (size_t)D_MODELX * D_MODELX * 2;  // 1.18 MB
  short* Xb  = (short*)(ws);
  short* Wqb = (short*)(ws + SZ_X);
  short* Wkb = (short*)(ws + SZ_X + SZ_W);
  short* Wvb = (short*)(ws + SZ_X + 2 * SZ_W);
  short* Wyb = (short*)(ws + SZ_X + 3 * SZ_W);
  short* Qb  = (short*)(ws + SZ_X + 4 * SZ_W);
  short* Kb  = (short*)(ws + 2 * SZ_X + 4 * SZ_W);
  short* VTb = (short*)(ws + 3 * SZ_X + 4 * SZ_W);  // V written transposed by GEMM
  short* Ab  = Xb;  // alias: Xb dead after QKV GEMM

  convert_all<<<2048, 256, 0, stream>>>(
      (const float4*)hs, (const float4*)Wq, (const float4*)Wk, (const float4*)Wv, (const float4*)Wy,
      (s16x4*)Xb, (s16x4*)Wqb, (s16x4*)Wkb, (s16x4*)Wvb, (s16x4*)Wyb);

  // fused QKV projections; Q pre-scaled by log2(e)/sqrt(64) (softmax in exp2 units);
  // V (z==2) stored directly transposed as VT[b][h][d][s]
  gemm_kernel<false, true><<<dim3(M_ROWS / 128, D_MODELX / 128, 3), 256, 0, stream>>>(
      Xb, Wqb, Wkb, Wvb, bq, bk, bv, (void*)Qb, (void*)Kb, (void*)VTb, 0.18033688011112042f);

  attn2<<<dim3(S_LEN / 128, N_HEADS, BATCHX), 256, 0, stream>>>(Qb, Kb, VTb, mask, Ab);

  // output projection -> fp32 d_out
  gemm_kernel<true, false><<<dim3(M_ROWS / 128, D_MODELX / 128, 1), 256, 0, stream>>>(
      Ab, Wyb, Wyb, Wyb, by, by, by, d_out, d_out, d_out, 1.0f);
}

// Round 12
// 287.553 us; speedup vs baseline: 1.8049x; 1.8049x over previous
//
#include <hip/hip_runtime.h>
#include <stdint.h>

#define S_LEN 2048
#define D_MODELX 768
#define N_HEADS 12
#define HEAD_D 64
#define BATCHX 4
#define M_ROWS (BATCHX * S_LEN)  // 8192

typedef __attribute__((ext_vector_type(8))) short bf16x8;
typedef __attribute__((ext_vector_type(4))) short s16x4;
typedef __attribute__((ext_vector_type(4))) float f32x4;
typedef __attribute__((ext_vector_type(16))) float f32x16;
typedef __attribute__((ext_vector_type(4))) uint32_t u32x4;

#define CROW(r_, hi_) (((r_) & 3) + 8 * ((r_) >> 2) + 4 * (hi_))

__device__ __forceinline__ short bf16_rne(float f) {
  uint32_t u = __builtin_bit_cast(uint32_t, f);
  u += 0x7FFFu + ((u >> 16) & 1u);
  return (short)(u >> 16);
}

__device__ __forceinline__ void gload_lds16(const void* g, void* l) {
  __builtin_amdgcn_global_load_lds((const __attribute__((address_space(1))) void*)g,
                                   (__attribute__((address_space(3))) void*)l, 16, 0, 0);
}

// ---------------- fused fp32 -> bf16 convert (X + 4 weight matrices) ----------------
__global__ __launch_bounds__(256) void convert_all(
    const float4* __restrict__ X,
    const float4* __restrict__ Wq, const float4* __restrict__ Wk,
    const float4* __restrict__ Wv, const float4* __restrict__ Wy,
    s16x4* __restrict__ Xb,
    s16x4* __restrict__ Wqb, s16x4* __restrict__ Wkb,
    s16x4* __restrict__ Wvb, s16x4* __restrict__ Wyb)
{
  const int NX = M_ROWS * D_MODELX / 4;
  const int NW = D_MODELX * D_MODELX / 4;
  const int NT = NX + 4 * NW;
  const int stride = gridDim.x * blockDim.x;
  for (int i = blockIdx.x * blockDim.x + threadIdx.x; i < NT; i += stride) {
    const float4* src; s16x4* dst; int off;
    if (i < NX)               { src = X;  dst = Xb;  off = i; }
    else if (i < NX + NW)     { src = Wq; dst = Wqb; off = i - NX; }
    else if (i < NX + 2*NW)   { src = Wk; dst = Wkb; off = i - NX - NW; }
    else if (i < NX + 3*NW)   { src = Wv; dst = Wvb; off = i - NX - 2*NW; }
    else                      { src = Wy; dst = Wyb; off = i - NX - 3*NW; }
    float4 v = src[off];
    s16x4 o;
    o.x = bf16_rne(v.x); o.y = bf16_rne(v.y); o.z = bf16_rne(v.z); o.w = bf16_rne(v.w);
    dst[off] = o;
  }
}

// ---------------- bf16 GEMM:  Out[M,N] = A[M,K] @ W[N,K]^T + bias ----------------
template<bool OUTF32, bool VTOUT>
__global__ __launch_bounds__(256) void gemm_kernel(
    const short* __restrict__ A,
    const short* __restrict__ W0, const short* __restrict__ W1, const short* __restrict__ W2,
    const float* __restrict__ b0, const float* __restrict__ b1, const float* __restrict__ b2,
    void* __restrict__ O0, void* __restrict__ O1, void* __restrict__ O2,
    float scale0)
{
  const int K = D_MODELX, N = D_MODELX;
  const int z = blockIdx.z;
  const short* W    = (z == 0) ? W0 : ((z == 1) ? W1 : W2);
  const float* bias = (z == 0) ? b0 : ((z == 1) ? b1 : b2);
  void* Op          = (z == 0) ? O0 : ((z == 1) ? O1 : O2);
  const float scale = (z == 0) ? scale0 : 1.0f;

  const int tid = threadIdx.x;
  const int lane = tid & 63;
  const int wv = tid >> 6;
  const int wm = wv >> 1, wn = wv & 1;
  const int r = lane & 15, g = lane >> 4;

  const int m0 = blockIdx.x * 128;
  const int n0 = blockIdx.y * 128;

  __shared__ short As[2][128 * 32];
  __shared__ short Bs[2][128 * 32];

  const f32x4 fzero = {0.f, 0.f, 0.f, 0.f};
  f32x4 acc[4][4];
  #pragma unroll
  for (int i = 0; i < 4; ++i)
    #pragma unroll
    for (int j = 0; j < 4; ++j) acc[i][j] = fzero;

  const int row_s = lane >> 2;
  const int colb  = (lane & 3) * 16;

  auto stage = [&](int buf, int kt) {
    const int kc = kt * 32;
    #pragma unroll
    for (int it = 0; it < 2; ++it) {
      int chunk = wv * 2 + it;
      int row = chunk * 16 + row_s;
      const char* gA = (const char*)(A + (size_t)(m0 + row) * K + kc) + colb;
      const char* gB = (const char*)(W + (size_t)(n0 + row) * K + kc) + colb;
      gload_lds16(gA, (char*)(&As[buf][0]) + chunk * 1024);
      gload_lds16(gB, (char*)(&Bs[buf][0]) + chunk * 1024);
    }
  };

  const int NTK = K / 32;
  stage(0, 0);
  asm volatile("s_waitcnt vmcnt(0)");
  __syncthreads();

  int cur = 0;
  for (int kt = 0; kt < NTK; ++kt) {
    if (kt + 1 < NTK) stage(cur ^ 1, kt + 1);
    bf16x8 af[4], bfr[4];
    #pragma unroll
    for (int i = 0; i < 4; ++i)
      af[i] = *(const bf16x8*)(&As[cur][(wm * 64 + i * 16 + r) * 32 + g * 8]);
    #pragma unroll
    for (int j = 0; j < 4; ++j)
      bfr[j] = *(const bf16x8*)(&Bs[cur][(wn * 64 + j * 16 + r) * 32 + g * 8]);
    #pragma unroll
    for (int i = 0; i < 4; ++i)
      #pragma unroll
      for (int j = 0; j < 4; ++j)
        acc[i][j] = __builtin_amdgcn_mfma_f32_16x16x32_bf16(af[i], bfr[j], acc[i][j], 0, 0, 0);
    asm volatile("s_waitcnt vmcnt(0)");
    __syncthreads();
    cur ^= 1;
  }

  if (VTOUT && z == 2) {
    #pragma unroll
    for (int j = 0; j < 4; ++j) {
      const int col = n0 + wn * 64 + j * 16 + r;
      const float bv_ = bias[col];
      const int hh = col >> 6, dd = col & 63;
      #pragma unroll
      for (int i = 0; i < 4; ++i) {
        const int rowb = m0 + wm * 64 + i * 16 + g * 4;
        const int bb = rowb >> 11, ss = rowb & 2047;
        s16x4 pk;
        #pragma unroll
        for (int e = 0; e < 4; ++e) pk[e] = bf16_rne(acc[i][j][e] + bv_);
        *(s16x4*)((short*)Op + ((size_t)(bb * N_HEADS + hh) * HEAD_D + dd) * S_LEN + ss) = pk;
      }
    }
    return;
  }

  #pragma unroll
  for (int j = 0; j < 4; ++j) {
    const int col = n0 + wn * 64 + j * 16 + r;
    const float bv_ = bias[col];
    #pragma unroll
    for (int i = 0; i < 4; ++i) {
      const int rowb = m0 + wm * 64 + i * 16 + g * 4;
      #pragma unroll
      for (int e = 0; e < 4; ++e) {
        float v = (acc[i][j][e] + bv_) * scale;
        if (OUTF32) ((float*)Op)[(size_t)(rowb + e) * N + col] = v;
        else        ((short*)Op)[(size_t)(rowb + e) * N + col] = bf16_rne(v);
      }
    }
  }
}

// ---------------- flash attention v3: swapped QK^T + LDS-staged K/V + kv-split -----
// 512 threads = 8 waves = 4 q-waves x 2 kv-splits. KVBLK=32, double-buffered LDS,
// 16B XOR-swizzle (pre-swizzled global src for global_load_lds, swizzled ds_read).
// K key = (row&7) on 8 slots; V key = ((row>>1)&3) on 4 slots (row stride 64B:
// rows alias mod 2, so key must vary with row>>1 to break the 8-way set).
// Q pre-scaled by 0.125*log2(e). Lane holds scores for q = lane&31 (swapped MFMA).
__global__ __launch_bounds__(512, 4) void attn3(
    const short* __restrict__ Q, const short* __restrict__ Kgl,
    const short* __restrict__ VT, const int* __restrict__ mask,
    short* __restrict__ O)
{
  const int b = blockIdx.z, h = blockIdx.y;
  const int tid = threadIdx.x;
  const int lane = tid & 63;
  const int wv = tid >> 6;          // 0..7
  const int wq = wv & 3;            // q-wave
  const int ws = wv >> 2;           // kv-split half
  const int gtid = tid & 255;       // id within split-group
  const int qc = lane & 31;
  const int hi = lane >> 5;
  const int q0 = blockIdx.x * 128 + wq * 32;
  const size_t hb  = (size_t)b * S_LEN * D_MODELX + h * HEAD_D;
  const size_t vtb = (size_t)(b * N_HEADS + h) * HEAD_D * S_LEN;

  // LDS: staging (32KB) unioned with epilogue combine buffers (~35KB)
  __shared__ __attribute__((aligned(16))) char LDSU[35840];
  __shared__ float Abuf[8][32];
  char* Kst = LDSU;                 // [2 grp][2 buf][4096] : 32 kv-rows x 128B swz
  char* Vst = LDSU + 16384;         // [2 grp][2 buf][4096] : 64 d-rows x 64B swz
  float* Mx  = (float*)LDSU;        // [2 ws][4 wq][32 q]
  float* Lx  = (float*)(LDSU + 1024);
  float* Obf = (float*)(LDSU + 2048); // [4 wq][64 lane][33] (pad-33)

  // Q B-frags (hoisted)
  bf16x8 qf[4];
  #pragma unroll
  for (int c = 0; c < 4; ++c)
    qf[c] = *(const bf16x8*)(Q + hb + (size_t)(q0 + qc) * D_MODELX + c * 16 + hi * 8);

  f32x16 o0 = {}, o1 = {};
  float mr = -1e30f, lr = 0.f;
  const int* mrow = mask + (size_t)b * S_LEN;

  // staging: group's 256 threads fetch K tile (32x128B) + VT tile (64x64B),
  // global source pre-swizzled so linear LDS dest == swizzled layout.
  const int krow_s = gtid >> 3, kslot = gtid & 7;
  const char* kg_base = (const char*)(Kgl + hb) + ((size_t)(kslot ^ (krow_s & 7)) << 4)
                        + (size_t)krow_s * (D_MODELX * 2);
  const int vrow_s = gtid >> 2, vslot = gtid & 3;
  const char* vg_base = (const char*)(VT + vtb) + ((size_t)(vslot ^ ((vrow_s >> 1) & 3)) << 4)
                        + (size_t)vrow_s * (S_LEN * 2);
  const int wofs = (gtid >> 6) * 1024;

  auto stage = [&](int bufn, int kvt) {
    const int kv0g = ws * 1024 + kvt * 32;
    gload_lds16(kg_base + (size_t)kv0g * (D_MODELX * 2), Kst + (ws * 2 + bufn) * 4096 + wofs);
    gload_lds16(vg_base + (size_t)kv0g * 2,              Vst + (ws * 2 + bufn) * 4096 + wofs);
  };

  stage(0, 0);
  asm volatile("s_waitcnt vmcnt(0)");
  __syncthreads();

  int cur = 0;
  for (int t = 0; t < 32; ++t) {
    if (t + 1 < 32) stage(cur ^ 1, t + 1);
    const char* Kb_ = Kst + (ws * 2 + cur) * 4096;
    const char* Vb_ = Vst + (ws * 2 + cur) * 4096;

    // ---- QK^T (swapped): one 32kv x 32q tile ----
    f32x16 sa = {};
    #pragma unroll
    for (int c = 0; c < 4; ++c) {
      bf16x8 kf = *(const bf16x8*)(Kb_ + qc * 128 + (((2 * c + hi) ^ (qc & 7)) << 4));
      sa = __builtin_amdgcn_mfma_f32_32x32x16_bf16(kf, qf[c], sa, 0, 0, 0);
    }

    // ---- mask (masked value -3e38: stays dominated even vs initial mr=-1e30) ----
    const int kvbase = ws * 1024 + t * 32;
    unsigned long long bal = __ballot(mrow[kvbase + qc] == 0);
    if (bal) {
      #pragma unroll
      for (int r = 0; r < 16; ++r)
        if ((bal >> CROW(r, hi)) & 1ull) sa[r] = -3e38f;
    }

    // ---- online softmax (log2 units, defer-max THR=8) ----
    float bm = -1e30f;
    #pragma unroll
    for (int r = 0; r < 16; ++r) bm = fmaxf(bm, sa[r]);
    bm = fmaxf(bm, __shfl_xor(bm, 32));

    if (!__all(bm <= mr + 8.0f)) {
      float mnew = fmaxf(mr, bm);
      float alpha = __builtin_amdgcn_exp2f(mr - mnew);
      mr = mnew;
      lr *= alpha;
      if (hi == 0) Abuf[wv][qc] = alpha;
      #pragma unroll
      for (int r = 0; r < 16; ++r) {
        float av = Abuf[wv][CROW(r, hi)];
        o0[r] *= av; o1[r] *= av;
      }
    }

    float rs = 0.f;
    #pragma unroll
    for (int r = 0; r < 16; ++r) {
      float p = __builtin_amdgcn_exp2f(sa[r] - mr);
      sa[r] = p;
      rs += p;
    }
    lr += rs;

    // ---- pack P -> bf16 (in-lane) ----
    uint32_t w[8];
    #pragma unroll
    for (int m = 0; m < 8; ++m)
      asm("v_cvt_pk_bf16_f32 %0, %1, %2"
          : "=v"(w[m]) : "v"(sa[2 * m]), "v"(sa[2 * m + 1]));

    // ---- PV: A = own P, B = swizzled V^T from LDS ----
    const char* vb0 = Vb_ + qc * 64;
    const char* vb1 = Vb_ + (32 + qc) * 64;
    const int vkey = (qc >> 1) & 3;  // same key for rows qc and 32+qc
    #pragma unroll
    for (int u = 0; u < 2; ++u) {
      u32x4 fw = {w[4 * u], w[4 * u + 1], w[4 * u + 2], w[4 * u + 3]};
      bf16x8 pa = __builtin_bit_cast(bf16x8, fw);
      const int sA = (((2 * u) ^ vkey) << 4) + 8 * hi;
      const int sB = (((2 * u + 1) ^ vkey) << 4) + 8 * hi;
      s16x4 a0 = *(const s16x4*)(vb0 + sA);
      s16x4 a1 = *(const s16x4*)(vb0 + sB);
      bf16x8 vf0 = __builtin_shufflevector(a0, a1, 0, 1, 2, 3, 4, 5, 6, 7);
      o0 = __builtin_amdgcn_mfma_f32_32x32x16_bf16(pa, vf0, o0, 0, 0, 0);
      s16x4 b0v = *(const s16x4*)(vb1 + sA);
      s16x4 b1v = *(const s16x4*)(vb1 + sB);
      bf16x8 vf1 = __builtin_shufflevector(b0v, b1v, 0, 1, 2, 3, 4, 5, 6, 7);
      o1 = __builtin_amdgcn_mfma_f32_32x32x16_bf16(pa, vf1, o1, 0, 0, 0);
    }

    __syncthreads();
    cur ^= 1;
  }

  // ---- epilogue: combine the two kv-halves (flash-decoding style), store ----
  float ltot = lr + __shfl_xor(lr, 32);
  if (hi == 0) {
    Mx[ws * 128 + wq * 32 + qc] = mr;
    Lx[ws * 128 + wq * 32 + qc] = ltot;
  }
  if (ws == 1) {
    float* ob = Obf + (wq * 64 + lane) * 33;
    #pragma unroll
    for (int r = 0; r < 16; ++r) { ob[r] = o0[r]; ob[16 + r] = o1[r]; }
  }
  __syncthreads();
  if (ws == 0) {
    const float* ob = Obf + (wq * 64 + lane) * 33;
    #pragma unroll
    for (int r = 0; r < 16; ++r) {
      const int qr = CROW(r, hi);
      float m0 = Mx[wq * 32 + qr], m1 = Mx[128 + wq * 32 + qr];
      float msx = fmaxf(m0, m1);
      float a0 = __builtin_amdgcn_exp2f(m0 - msx);
      float a1 = __builtin_amdgcn_exp2f(m1 - msx);
      float li = 1.0f / (Lx[wq * 32 + qr] * a0 + Lx[128 + wq * 32 + qr] * a1);
      const int q = q0 + qr;
      O[hb + (size_t)q * D_MODELX + qc]      = bf16_rne((o0[r] * a0 + ob[r] * a1) * li);
      O[hb + (size_t)q * D_MODELX + 32 + qc] = bf16_rne((o1[r] * a0 + ob[16 + r] * a1) * li);
    }
  }
}

// ---------------- host launch ----------------
extern "C" void kernel_launch(void* const* d_in, const int* in_sizes, int n_in,
                              void* d_out, int out_size, void* d_ws, size_t ws_size,
                              hipStream_t stream)
{
  const float* hs = (const float*)d_in[0];
  const int* mask = (const int*)d_in[1];
  const float* Wq = (const float*)d_in[2];
  const float* bq = (const float*)d_in[3];
  const float* Wk = (const float*)d_in[4];
  const float* bk = (const float*)d_in[5];
  const float* Wv = (const float*)d_in[6];
  const float* bv = (const float*)d_in[7];
  const float* Wy = (const float*)d_in[8];
  const float* by = (const float*)d_in[9];

  char* ws = (char*)d_ws;
  const size_t SZ_X = (size_t)M_ROWS * D_MODELX * 2;    // 12.6 MB
  const size_t SZ_W = (size_t)D_MODELX * D_MODELX * 2;  // 1.18 MB
  short* Xb  = (short*)(ws);
  short* Wqb = (short*)(ws + SZ_X);
  short* Wkb = (short*)(ws + SZ_X + SZ_W);
  short* Wvb = (short*)(ws + SZ_X + 2 * SZ_W);
  short* Wyb = (short*)(ws + SZ_X + 3 * SZ_W);
  short* Qb  = (short*)(ws + SZ_X + 4 * SZ_W);
  short* Kb  = (short*)(ws + 2 * SZ_X + 4 * SZ_W);
  short* VTb = (short*)(ws + 3 * SZ_X + 4 * SZ_W);  // V written transposed by GEMM
  short* Ab  = Xb;  // alias: Xb dead after QKV GEMM

  convert_all<<<2048, 256, 0, stream>>>(
      (const float4*)hs, (const float4*)Wq, (const float4*)Wk, (const float4*)Wv, (const float4*)Wy,
      (s16x4*)Xb, (s16x4*)Wqb, (s16x4*)Wkb, (s16x4*)Wvb, (s16x4*)Wyb);

  // fused QKV projections; Q pre-scaled by log2(e)/sqrt(64); V stored transposed
  gemm_kernel<false, true><<<dim3(M_ROWS / 128, D_MODELX / 128, 3), 256, 0, stream>>>(
      Xb, Wqb, Wkb, Wvb, bq, bk, bv, (void*)Qb, (void*)Kb, (void*)VTb, 0.18033688011112042f);

  attn3<<<dim3(S_LEN / 128, N_HEADS, BATCHX), 512, 0, stream>>>(Qb, Kb, VTb, mask, Ab);

  // output projection -> fp32 d_out
  gemm_kernel<true, false><<<dim3(M_ROWS / 128, D_MODELX / 128, 1), 256, 0, stream>>>(
      Ab, Wyb, Wyb, Wyb, by, by, by, d_out, d_out, d_out, 1.0f);
}